// Round 22
// baseline (35.735 us; speedup 1.0000x reference)
//
#include <hip/hip_runtime.h>

// ConvTranspose4d via bf16 MFMA (R22 = R21 + TRANSPOSED LDS [n][row], wide b64 reads).
// Gather: out[co,f,od,oh,ow] = sum_{ci,i,kd,kh,kw} x[ci,f+i,id,ih,iw]*W[ci,co,i,kd,kh,kw]
// Stack: R16 E/O fold (one MFMA/K-step); R17 LDS staging; R18 bf16-packed words;
//   R19 od-pair 8-wave blocks; R21 LSTR/addressing (35.7us best).
// R22: LDS transposed to [n][row], row = gg*6 + t*2 + e (e-minor). One MFMA's 4
//   B-quarters = 4 rows at lane's column n -> contiguous/near-contiguous per lane:
//   CLS0: rows {2th-2..2th+1} -> 2x ds_read_b64 (was 4x b32); CLS1: pairs at +0,+6 ->
//   2x b64; CLS2: {0,2,6,8} and CLS3: {0,6,12,18} singles (ds_read2-fusable, one base).
//   NRSTR=146: c15*146%32 = 16 distinct even banks -> b64 reads conflict-free.
//   A-table j-permutation re-derived for the new slot order (CLS0: KD=(j>>1)&1?2:0,
//   KH=(j>>2)&1?0:2; CLS2: KH flipped; CLS1/3 unchanged) - verified element-wise.
//   Same weights/bits/K-order -> absmax must stay EXACTLY 0.0078125 (gate).

typedef float  f32x4  __attribute__((ext_vector_type(4)));
typedef float  f4a    __attribute__((ext_vector_type(4)));
typedef short  bf16x8 __attribute__((ext_vector_type(8)));
typedef unsigned int u32;
typedef u32    u32x2  __attribute__((ext_vector_type(2)));
typedef u32    u32x4  __attribute__((ext_vector_type(4)));

namespace {
constexpr int T_ = 8, D_ = 24, H_ = 48, W_ = 48;
constexpr int TO = 6, DO_ = 47, HO = 95, WO = 95;
constexpr int XCS = T_ * D_ * H_ * W_;
constexpr int XFS = D_ * H_ * W_;
constexpr int XDS = H_ * W_;
constexpr long OCS = (long)TO * DO_ * HO * WO;
constexpr int OFS = DO_ * HO * WO;
constexpr int ODS = HO * WO;

constexpr int AG[4] = {24, 12, 12, 8};
constexpr int AOFF[4] = {0, 3072, 4608, 6144};         // shorts; total 7168 = 14 KB
constexpr int NRSTR = 146;                             // per-column row stride (u32)

__global__ __launch_bounds__(256) void pack_kernel(const float* __restrict__ w,
                                                   unsigned short* __restrict__ A) {
  const int tid = blockIdx.x * 256 + threadIdx.x;
  const int nthr = gridDim.x * 256;
  const int KR[4] = {192, 96, 96, 48};
  for (int c = 0; c < 4; ++c) {
    const int cnt = AG[c] * 128;                       // [g][r(16)][j(8)] shorts
    for (int e = tid; e < cnt; e += nthr) {
      const int j = e & 7, r = (e >> 3) & 15, g = e >> 7;
      const int k = g * 8 + j;
      float v = 0.f;
      if (k < KR[c]) {
        int gg = -1, kd = 1, kh = 1;
        const int cc = j & 1;
        if (c == 0)      { gg = g;               kd = ((j >> 1) & 1) ? 2 : 0; kh = ((j >> 2) & 1) ? 0 : 2; }
        else if (c == 1) { gg = 2 * g + (j >> 2); kd = ((j >> 1) & 1) ? 2 : 0; kh = 1; }
        else if (c == 2) { gg = 2 * g + (j >> 2); kd = 1; kh = ((j >> 1) & 1) ? 0 : 2; }
        else             { gg = 4 * g + (j >> 1); kd = 1; kh = 1; }
        if (gg >= 0 && gg < 24) {
          const int ci = gg / 3, i = gg - 3 * (gg / 3);
          const int co = r & 7;
          int kw = (r < 8) ? (cc == 0 ? 1 : -1) : (cc == 0 ? 2 : 0);
          if (kw >= 0) v = w[ci * 648 + co * 81 + i * 27 + kd * 9 + kh * 3 + kw];
        }
      }
      u32 u = __float_as_uint(v);
      u += 0x7FFFu + ((u >> 16) & 1u);                 // RNE to bf16
      A[AOFF[c] + e] = (unsigned short)(u >> 16);
    }
  }
}

template<int PD, int PH>
__device__ __forceinline__ void wave_body(
    const u32* __restrict__ lds, const unsigned short* __restrict__ A,
    float* __restrict__ out, int f, int od, int oh, int ihb, int lane)
{
  constexpr int CLS = (PD && PH) ? 0 : PD ? 1 : PH ? 2 : 3;
  constexpr int NSTEP = (CLS == 0) ? 6 : (CLS == 3) ? 2 : 3;
  const int c15 = lane & 15, q = lane >> 4;
  const int th = ((oh + PH) >> 1) - ihb;               // top h-row (0..2)

  bf16x8 af[NSTEP];
  {
    const unsigned short* Ap = A + AOFF[CLS] + c15 * 8;
    #pragma unroll
    for (int s = 0; s < NSTEP; ++s)
      af[s] = *reinterpret_cast<const bf16x8*>(Ap + (s * 4 + q) * 128);
  }

  f32x4 acc[3];
  #pragma unroll
  for (int b = 0; b < 3; ++b) acc[b] = {0, 0, 0, 0};

  // transposed layout: lds[n*NRSTR + row], row = gg*6 + t*2 + e
  #pragma unroll
  for (int blk = 0; blk < 3; ++blk) {
    const int n = blk * 16 + c15;
    const u32* col = lds + n * NRSTR;
    #pragma unroll
    for (int s = 0; s < NSTEP; ++s) {
      const int G = s * 4 + q;
      u32x4 ue;
      if constexpr (CLS == 0) {                        // rows 2th-2..2th+1 (contig)
        const u32* b = col + G * 6 + 2 * th - 2;
        const u32x2 lo = *reinterpret_cast<const u32x2*>(b);      // (th-1,e0),(th-1,e1)
        const u32x2 hi = *reinterpret_cast<const u32x2*>(b + 2);  // (th,e0),(th,e1)
        ue = u32x4{lo.x, lo.y, hi.x, hi.y};
      } else if constexpr (CLS == 1) {                 // (g0,e0),(g0,e1),(g1,e0),(g1,e1)
        const u32* b = col + 2 * G * 6 + 2 * th;
        const u32x2 lo = *reinterpret_cast<const u32x2*>(b);
        const u32x2 hi = *reinterpret_cast<const u32x2*>(b + 6);
        ue = u32x4{lo.x, lo.y, hi.x, hi.y};
      } else if constexpr (CLS == 2) {                 // (g0,th-1),(g0,th),(g1,th-1),(g1,th) e=1
        const u32* b = col + 2 * G * 6 + 2 * th - 1;
        ue = u32x4{b[0], b[2], b[6], b[8]};
      } else {                                         // g ascending, e=1, t=th
        const int g4 = (G > 5) ? 20 : 4 * G;           // G>5 -> A==0 (k>=48), any row fine
        const u32* b = col + g4 * 6 + 2 * th + 1;
        ue = u32x4{b[0], b[6], b[12], b[18]};
      }
      acc[blk] = __builtin_amdgcn_mfma_f32_16x16x32_bf16(af[s], __builtin_bit_cast(bf16x8, ue), acc[blk], 0, 0, 0);
    }
  }

  // D rows 0-7 = co (even ow), 8-15 = co (odd ow); row = q*4+j, col = c15.
  const int isO = (q >= 2);
  const int co0 = (q & 1) * 4;
  #pragma unroll
  for (int blk = 0; blk < 3; ++blk) {
    const int ow = blk * 32 + 2 * c15 + isO;
    if (ow < 95) {
      const long ob = (long)f * OFS + (long)od * ODS + (long)oh * HO + ow;
      #pragma unroll
      for (int j = 0; j < 4; ++j)
        out[(long)(co0 + j) * OCS + ob] = acc[blk][j];
    }
  }
}

constexpr int NBLK = 6 * 24 * 24;                      // f x od-pair x og = 3456

__global__ __launch_bounds__(512) void convt4d_kernel(
    const float* __restrict__ x, const unsigned short* __restrict__ A,
    float* __restrict__ out)
{
  __shared__ u32 lds[48 * NRSTR];                      // 28032 B

  constexpr int qq = NBLK / 8;                         // 432 (NBLK%8==0)
  const int bid = blockIdx.x;
  const int L = (bid & 7) * qq + (bid >> 3);           // bijective XCD swizzle
  const int og = L % 24;
  const int rest = L / 24;
  const int odp = rest % 24, f = rest / 24;            // od pair: {2*odp, 2*odp+1}

  const int tid = threadIdx.x;
  const int ihb = og * 2;
  const int idp = odp + 1;                             // e=0 plane = p+1, e=1 plane = p

  // stage 144-row union PRE-PACKED + TRANSPOSED: lds[n*NRSTR + row] =
  //   bf(x[n]) | bf(x[n+1])<<16 ; row = gg*6 + t*2 + e
  for (int c = tid; c < 144 * 12; c += 512) {
    const int row = c / 12, ch = c % 12;
    const int gg = row / 6;
    const int rem = row % 6;
    const int t = rem >> 1, e = rem & 1;
    const int i = gg % 3, ci = gg / 3;
    int plane = idp - e; if (plane > 23) plane = 23;   // odp=23,e=0: unused, clamp OOB
    int ih = ihb + t; if (ih > 47) ih = 47;            // og=23 t=2: unused, clamp
    const float* src = x + ci * XCS + (f + i) * XFS + plane * XDS + ih * W_ + ch * 4;
    const f4a v = *reinterpret_cast<const f4a*>(src);
    const float v4 = (ch == 11) ? 0.f : src[4];        // x[48] slot must be 0 (n=47 pair)
    const u32 b0 = __float_as_uint(v.x), b1 = __float_as_uint(v.y);
    const u32 b2 = __float_as_uint(v.z), b3 = __float_as_uint(v.w);
    const u32 b4 = __float_as_uint(v4);
    u32* dst = lds + (4 * ch) * NRSTR + row;
    dst[0 * NRSTR] = __builtin_amdgcn_perm(b1, b0, 0x07060302u);
    dst[1 * NRSTR] = __builtin_amdgcn_perm(b2, b1, 0x07060302u);
    dst[2 * NRSTR] = __builtin_amdgcn_perm(b3, b2, 0x07060302u);
    dst[3 * NRSTR] = __builtin_amdgcn_perm(b4, b3, 0x07060302u);
  }
  __syncthreads();

  const int w = tid >> 6, lane = tid & 63;
  const int half = w >> 2;                             // 0: od=2p (pd0), 1: od=2p+1 (pd1)
  const int od = 2 * odp + half;
  if (od > 46) return;                                 // odp=23 pd1 half: no od=47
  int oh = og * 4 + (w & 3);
  if (oh > 94) oh = 93;                                // og=23,w&3=3: dup of w&3=1 (benign)
  if (half) {
    if (oh & 1) wave_body<1, 1>(lds, A, out, f, od, oh, ihb, lane);
    else        wave_body<1, 0>(lds, A, out, f, od, oh, ihb, lane);
  } else {
    if (oh & 1) wave_body<0, 1>(lds, A, out, f, od, oh, ihb, lane);
    else        wave_body<0, 0>(lds, A, out, f, od, oh, ihb, lane);
  }
}
}  // namespace

extern "C" void kernel_launch(void* const* d_in, const int* in_sizes, int n_in,
                              void* d_out, int out_size, void* d_ws, size_t ws_size,
                              hipStream_t stream) {
  const float* x = (const float*)d_in[0];
  const float* w = (const float*)d_in[1];
  float* out = (float*)d_out;
  unsigned short* A = (unsigned short*)d_ws;           // 7168 shorts = 14 KB
  hipLaunchKernelGGL(pack_kernel, dim3(8), dim3(256), 0, stream, w, A);
  hipLaunchKernelGGL(convt4d_kernel, dim3(NBLK), dim3(512), 0, stream, x, A, out);
}

// Round 23
// 33.369 us; speedup vs baseline: 1.0709x; 1.0709x over previous
//
#include <hip/hip_runtime.h>

// ConvTranspose4d via bf16 MFMA (R23 = R22 + f-PAIR waves: each wave computes f0,f0+1).
// Gather: out[co,f,od,oh,ow] = sum_{ci,i,kd,kh,kw} x[ci,f+i,id,ih,iw]*W[ci,co,i,kd,kh,kw]
// Stack: R16 E/O fold; R17 LDS staging; R18 bf16-packed words; R19 od-pair 8-wave
//   blocks; R21 addressing; R22 transposed [n][row] layout (verified, neutral).
// R23: block stages frames f0..f0+3 (192 rows, was 144 for 3 frames) serving TWO f
//   tiles per wave -> stage/output x0.67, blocks 3456->1728 (fixed costs halve),
//   compute phase doubles (better stage-latency coverage). 512 thr kept (R20 lesson).
//   Row index rowb(gg,dl) = ((gg/3)*4 + gg%3 + dl)*6; NRSTR=194 (same bank structure
//   as 146: = 2 mod 4 -> 16 even banks across c15; b64-aligned bases stay even).
//   Per-output math order/bits unchanged -> absmax must stay EXACTLY 0.0078125 (gate).

typedef float  f32x4  __attribute__((ext_vector_type(4)));
typedef float  f4a    __attribute__((ext_vector_type(4)));
typedef short  bf16x8 __attribute__((ext_vector_type(8)));
typedef unsigned int u32;
typedef u32    u32x2  __attribute__((ext_vector_type(2)));
typedef u32    u32x4  __attribute__((ext_vector_type(4)));

namespace {
constexpr int T_ = 8, D_ = 24, H_ = 48, W_ = 48;
constexpr int TO = 6, DO_ = 47, HO = 95, WO = 95;
constexpr int XCS = T_ * D_ * H_ * W_;
constexpr int XFS = D_ * H_ * W_;
constexpr int XDS = H_ * W_;
constexpr long OCS = (long)TO * DO_ * HO * WO;
constexpr int OFS = DO_ * HO * WO;
constexpr int ODS = HO * WO;

constexpr int AG[4] = {24, 12, 12, 8};
constexpr int AOFF[4] = {0, 3072, 4608, 6144};         // shorts; total 7168 = 14 KB
constexpr int NRSTR = 194;                             // per-column row stride (u32)

__global__ __launch_bounds__(256) void pack_kernel(const float* __restrict__ w,
                                                   unsigned short* __restrict__ A) {
  const int tid = blockIdx.x * 256 + threadIdx.x;
  const int nthr = gridDim.x * 256;
  const int KR[4] = {192, 96, 96, 48};
  for (int c = 0; c < 4; ++c) {
    const int cnt = AG[c] * 128;                       // [g][r(16)][j(8)] shorts
    for (int e = tid; e < cnt; e += nthr) {
      const int j = e & 7, r = (e >> 3) & 15, g = e >> 7;
      const int k = g * 8 + j;
      float v = 0.f;
      if (k < KR[c]) {
        int gg = -1, kd = 1, kh = 1;
        const int cc = j & 1;
        if (c == 0)      { gg = g;               kd = ((j >> 1) & 1) ? 2 : 0; kh = ((j >> 2) & 1) ? 0 : 2; }
        else if (c == 1) { gg = 2 * g + (j >> 2); kd = ((j >> 1) & 1) ? 2 : 0; kh = 1; }
        else if (c == 2) { gg = 2 * g + (j >> 2); kd = 1; kh = ((j >> 1) & 1) ? 0 : 2; }
        else             { gg = 4 * g + (j >> 1); kd = 1; kh = 1; }
        if (gg >= 0 && gg < 24) {
          const int ci = gg / 3, i = gg - 3 * (gg / 3);
          const int co = r & 7;
          int kw = (r < 8) ? (cc == 0 ? 1 : -1) : (cc == 0 ? 2 : 0);
          if (kw >= 0) v = w[ci * 648 + co * 81 + i * 27 + kd * 9 + kh * 3 + kw];
        }
      }
      u32 u = __float_as_uint(v);
      u += 0x7FFFu + ((u >> 16) & 1u);                 // RNE to bf16
      A[AOFF[c] + e] = (unsigned short)(u >> 16);
    }
  }
}

// row group base for (gg = ci*3+i, dl = f-offset): gg' = ci*4 + i + dl; 6 rows per gg'
__device__ __forceinline__ int rowb(int gg, int dl) {
  const int ci = gg / 3;
  return (ci * 4 + (gg - 3 * ci) + dl) * 6;
}

template<int PD, int PH>
__device__ __forceinline__ void wave_body(
    const u32* __restrict__ lds, const unsigned short* __restrict__ A,
    float* __restrict__ out, int f0, int od, int oh, int ihb, int lane)
{
  constexpr int CLS = (PD && PH) ? 0 : PD ? 1 : PH ? 2 : 3;
  constexpr int NSTEP = (CLS == 0) ? 6 : (CLS == 3) ? 2 : 3;
  const int c15 = lane & 15, q = lane >> 4;
  const int th = ((oh + PH) >> 1) - ihb;               // top h-row (0..2)

  bf16x8 af[NSTEP];
  {
    const unsigned short* Ap = A + AOFF[CLS] + c15 * 8;
    #pragma unroll
    for (int s = 0; s < NSTEP; ++s)
      af[s] = *reinterpret_cast<const bf16x8*>(Ap + (s * 4 + q) * 128);
  }

  f32x4 acc[2][3];
  #pragma unroll
  for (int dl = 0; dl < 2; ++dl)
    #pragma unroll
    for (int b = 0; b < 3; ++b) acc[dl][b] = {0, 0, 0, 0};

  #pragma unroll
  for (int blk = 0; blk < 3; ++blk) {
    const int n = blk * 16 + c15;
    const u32* col = lds + n * NRSTR;
    #pragma unroll
    for (int s = 0; s < NSTEP; ++s) {
      const int G = s * 4 + q;
      #pragma unroll
      for (int dl = 0; dl < 2; ++dl) {
        u32x4 ue;
        if constexpr (CLS == 0) {                      // rows rowb + {2th-2..2th+1}
          const u32* b = col + rowb(G, dl) + 2 * th - 2;
          const u32x2 lo = *reinterpret_cast<const u32x2*>(b);
          const u32x2 hi = *reinterpret_cast<const u32x2*>(b + 2);
          ue = u32x4{lo.x, lo.y, hi.x, hi.y};
        } else if constexpr (CLS == 1) {               // (g0,e0),(g0,e1),(g1,e0),(g1,e1)
          const u32* b0 = col + rowb(2 * G, dl) + 2 * th;
          const u32* b1 = col + rowb(2 * G + 1, dl) + 2 * th;
          const u32x2 lo = *reinterpret_cast<const u32x2*>(b0);
          const u32x2 hi = *reinterpret_cast<const u32x2*>(b1);
          ue = u32x4{lo.x, lo.y, hi.x, hi.y};
        } else if constexpr (CLS == 2) {               // (g,th-1),(g,th) e=1 pairs
          const int r0 = rowb(2 * G, dl), r1 = rowb(2 * G + 1, dl);
          ue = u32x4{col[r0 + 2 * th - 1], col[r0 + 2 * th + 1],
                     col[r1 + 2 * th - 1], col[r1 + 2 * th + 1]};
        } else {                                       // g ascending, e=1, t=th
          #pragma unroll
          for (int d = 0; d < 4; ++d) {
            int gg = 4 * G + d; gg = (gg > 23) ? 23 : gg;  // k>=48 -> A==0, row dontcare
            ue[d] = col[rowb(gg, dl) + 2 * th + 1];
          }
        }
        acc[dl][blk] = __builtin_amdgcn_mfma_f32_16x16x32_bf16(af[s], __builtin_bit_cast(bf16x8, ue), acc[dl][blk], 0, 0, 0);
      }
    }
  }

  // D rows 0-7 = co (even ow), 8-15 = co (odd ow); row = q*4+j, col = c15.
  const int isO = (q >= 2);
  const int co0 = (q & 1) * 4;
  #pragma unroll
  for (int dl = 0; dl < 2; ++dl) {
    #pragma unroll
    for (int blk = 0; blk < 3; ++blk) {
      const int ow = blk * 32 + 2 * c15 + isO;
      if (ow < 95) {
        const long ob = (long)(f0 + dl) * OFS + (long)od * ODS + (long)oh * HO + ow;
        #pragma unroll
        for (int j = 0; j < 4; ++j)
          out[(long)(co0 + j) * OCS + ob] = acc[dl][blk][j];
      }
    }
  }
}

constexpr int NBLK = 3 * 24 * 24;                      // f-pair x od-pair x og = 1728

__global__ __launch_bounds__(512) void convt4d_kernel(
    const float* __restrict__ x, const unsigned short* __restrict__ A,
    float* __restrict__ out)
{
  __shared__ u32 lds[48 * NRSTR];                      // 37248 B

  constexpr int qq = NBLK / 8;                         // 216 (NBLK%8==0)
  const int bid = blockIdx.x;
  const int L = (bid & 7) * qq + (bid >> 3);           // bijective XCD swizzle
  const int og = L % 24;
  const int rest = L / 24;
  const int odp = rest % 24, fp = rest / 24;           // od pair {2odp,2odp+1}; f pair
  const int f0 = 2 * fp;                               // f0 in {0,2,4}; frames f0..f0+3

  const int tid = threadIdx.x;
  const int ihb = og * 2;
  const int idp = odp + 1;                             // e=0 plane = p+1, e=1 plane = p

  // stage 192-row union PRE-PACKED + TRANSPOSED: lds[n*NRSTR + row] =
  //   bf(x[n]) | bf(x[n+1])<<16 ; row = (ci*4 + fi)*6 + t*2 + e, fi = frame - f0 (0..3)
  for (int c = tid; c < 192 * 12; c += 512) {
    const int row = c / 12, ch = c % 12;
    const int ggp = row / 6;
    const int rem = row % 6;
    const int t = rem >> 1, e = rem & 1;
    const int ci = ggp >> 2, fi = ggp & 3;
    int plane = idp - e; if (plane > 23) plane = 23;   // odp=23,e=0: unused, clamp OOB
    int ih = ihb + t; if (ih > 47) ih = 47;            // og=23 t=2: unused, clamp
    const float* src = x + ci * XCS + (f0 + fi) * XFS + plane * XDS + ih * W_ + ch * 4;
    const f4a v = *reinterpret_cast<const f4a*>(src);
    const float v4 = (ch == 11) ? 0.f : src[4];        // x[48] slot must be 0 (n=47 pair)
    const u32 b0 = __float_as_uint(v.x), b1 = __float_as_uint(v.y);
    const u32 b2 = __float_as_uint(v.z), b3 = __float_as_uint(v.w);
    const u32 b4 = __float_as_uint(v4);
    u32* dst = lds + (4 * ch) * NRSTR + row;
    dst[0 * NRSTR] = __builtin_amdgcn_perm(b1, b0, 0x07060302u);
    dst[1 * NRSTR] = __builtin_amdgcn_perm(b2, b1, 0x07060302u);
    dst[2 * NRSTR] = __builtin_amdgcn_perm(b3, b2, 0x07060302u);
    dst[3 * NRSTR] = __builtin_amdgcn_perm(b4, b3, 0x07060302u);
  }
  __syncthreads();

  const int w = tid >> 6, lane = tid & 63;
  const int half = w >> 2;                             // 0: od=2p (pd0), 1: od=2p+1 (pd1)
  const int od = 2 * odp + half;
  if (od > 46) return;                                 // odp=23 pd1 half: no od=47
  int oh = og * 4 + (w & 3);
  if (oh > 94) oh = 93;                                // og=23,w&3=3: dup of w&3=1 (benign)
  if (half) {
    if (oh & 1) wave_body<1, 1>(lds, A, out, f0, od, oh, ihb, lane);
    else        wave_body<1, 0>(lds, A, out, f0, od, oh, ihb, lane);
  } else {
    if (oh & 1) wave_body<0, 1>(lds, A, out, f0, od, oh, ihb, lane);
    else        wave_body<0, 0>(lds, A, out, f0, od, oh, ihb, lane);
  }
}
}  // namespace

extern "C" void kernel_launch(void* const* d_in, const int* in_sizes, int n_in,
                              void* d_out, int out_size, void* d_ws, size_t ws_size,
                              hipStream_t stream) {
  const float* x = (const float*)d_in[0];
  const float* w = (const float*)d_in[1];
  float* out = (float*)d_out;
  unsigned short* A = (unsigned short*)d_ws;           // 7168 shorts = 14 KB
  hipLaunchKernelGGL(pack_kernel, dim3(8), dim3(256), 0, stream, w, A);
  hipLaunchKernelGGL(convt4d_kernel, dim3(NBLK), dim3(512), 0, stream, x, A, out);
}

// Round 24
// 32.875 us; speedup vs baseline: 1.0870x; 1.0150x over previous
//
#include <hip/hip_runtime.h>

// ConvTranspose4d via bf16 MFMA (R24 = R23 + f-TRIPLE waves: f0, f0+1, f0+2 per wave).
// Gather: out[co,f,od,oh,ow] = sum_{ci,i,kd,kh,kw} x[ci,f+i,id,ih,iw]*W[ci,co,i,kd,kh,kw]
// Stack: R16 E/O fold; R17 LDS staging; R18 bf16-packed words; R19 od-pair 8-wave
//   blocks; R21 addressing; R22 transposed [n][row]; R23 f-pair (33.4us best).
// R24: block stages frames f0..f0+4 (240 rows) serving THREE f-tiles per wave ->
//   stage/output x0.83, blocks 1728->1152, compute phase x1.5. 512 thr kept.
//   rowb(gg,dl) = ((gg/3)*5 + gg%3 + dl)*6; NRSTR=242 (242%32=18 -> c15*NRSTR%32
//   spans 16 distinct even banks, same property as R22's 146; b64 bases stay even).
//   f0 = 3*fp, fp in {0,1} -> frames {0..2},{3..5} cover all 6 outputs.
//   Per-output math order/bits unchanged -> absmax must stay EXACTLY 0.0078125 (gate).

typedef float  f32x4  __attribute__((ext_vector_type(4)));
typedef float  f4a    __attribute__((ext_vector_type(4)));
typedef short  bf16x8 __attribute__((ext_vector_type(8)));
typedef unsigned int u32;
typedef u32    u32x2  __attribute__((ext_vector_type(2)));
typedef u32    u32x4  __attribute__((ext_vector_type(4)));

namespace {
constexpr int T_ = 8, D_ = 24, H_ = 48, W_ = 48;
constexpr int TO = 6, DO_ = 47, HO = 95, WO = 95;
constexpr int XCS = T_ * D_ * H_ * W_;
constexpr int XFS = D_ * H_ * W_;
constexpr int XDS = H_ * W_;
constexpr long OCS = (long)TO * DO_ * HO * WO;
constexpr int OFS = DO_ * HO * WO;
constexpr int ODS = HO * WO;

constexpr int AG[4] = {24, 12, 12, 8};
constexpr int AOFF[4] = {0, 3072, 4608, 6144};         // shorts; total 7168 = 14 KB
constexpr int NRSTR = 242;                             // per-column row stride (u32)

__global__ __launch_bounds__(256) void pack_kernel(const float* __restrict__ w,
                                                   unsigned short* __restrict__ A) {
  const int tid = blockIdx.x * 256 + threadIdx.x;
  const int nthr = gridDim.x * 256;
  const int KR[4] = {192, 96, 96, 48};
  for (int c = 0; c < 4; ++c) {
    const int cnt = AG[c] * 128;                       // [g][r(16)][j(8)] shorts
    for (int e = tid; e < cnt; e += nthr) {
      const int j = e & 7, r = (e >> 3) & 15, g = e >> 7;
      const int k = g * 8 + j;
      float v = 0.f;
      if (k < KR[c]) {
        int gg = -1, kd = 1, kh = 1;
        const int cc = j & 1;
        if (c == 0)      { gg = g;               kd = ((j >> 1) & 1) ? 2 : 0; kh = ((j >> 2) & 1) ? 0 : 2; }
        else if (c == 1) { gg = 2 * g + (j >> 2); kd = ((j >> 1) & 1) ? 2 : 0; kh = 1; }
        else if (c == 2) { gg = 2 * g + (j >> 2); kd = 1; kh = ((j >> 1) & 1) ? 0 : 2; }
        else             { gg = 4 * g + (j >> 1); kd = 1; kh = 1; }
        if (gg >= 0 && gg < 24) {
          const int ci = gg / 3, i = gg - 3 * (gg / 3);
          const int co = r & 7;
          int kw = (r < 8) ? (cc == 0 ? 1 : -1) : (cc == 0 ? 2 : 0);
          if (kw >= 0) v = w[ci * 648 + co * 81 + i * 27 + kd * 9 + kh * 3 + kw];
        }
      }
      u32 u = __float_as_uint(v);
      u += 0x7FFFu + ((u >> 16) & 1u);                 // RNE to bf16
      A[AOFF[c] + e] = (unsigned short)(u >> 16);
    }
  }
}

// row group base for (gg = ci*3+i, dl = f-offset 0..2): gg' = ci*5 + i + dl
__device__ __forceinline__ int rowb(int gg, int dl) {
  const int ci = gg / 3;
  return (ci * 5 + (gg - 3 * ci) + dl) * 6;
}

template<int PD, int PH>
__device__ __forceinline__ void wave_body(
    const u32* __restrict__ lds, const unsigned short* __restrict__ A,
    float* __restrict__ out, int f0, int od, int oh, int ihb, int lane)
{
  constexpr int CLS = (PD && PH) ? 0 : PD ? 1 : PH ? 2 : 3;
  constexpr int NSTEP = (CLS == 0) ? 6 : (CLS == 3) ? 2 : 3;
  const int c15 = lane & 15, q = lane >> 4;
  const int th = ((oh + PH) >> 1) - ihb;               // top h-row (0..2)

  bf16x8 af[NSTEP];
  {
    const unsigned short* Ap = A + AOFF[CLS] + c15 * 8;
    #pragma unroll
    for (int s = 0; s < NSTEP; ++s)
      af[s] = *reinterpret_cast<const bf16x8*>(Ap + (s * 4 + q) * 128);
  }

  f32x4 acc[3][3];                                     // [dl][blk]
  #pragma unroll
  for (int dl = 0; dl < 3; ++dl)
    #pragma unroll
    for (int b = 0; b < 3; ++b) acc[dl][b] = {0, 0, 0, 0};

  #pragma unroll
  for (int blk = 0; blk < 3; ++blk) {
    const int n = blk * 16 + c15;
    const u32* col = lds + n * NRSTR;
    #pragma unroll
    for (int s = 0; s < NSTEP; ++s) {
      const int G = s * 4 + q;
      #pragma unroll
      for (int dl = 0; dl < 3; ++dl) {
        u32x4 ue;
        if constexpr (CLS == 0) {                      // rows rowb + {2th-2..2th+1}
          const u32* b = col + rowb(G, dl) + 2 * th - 2;
          const u32x2 lo = *reinterpret_cast<const u32x2*>(b);
          const u32x2 hi = *reinterpret_cast<const u32x2*>(b + 2);
          ue = u32x4{lo.x, lo.y, hi.x, hi.y};
        } else if constexpr (CLS == 1) {               // (g0,e0),(g0,e1),(g1,e0),(g1,e1)
          const u32* b0 = col + rowb(2 * G, dl) + 2 * th;
          const u32* b1 = col + rowb(2 * G + 1, dl) + 2 * th;
          const u32x2 lo = *reinterpret_cast<const u32x2*>(b0);
          const u32x2 hi = *reinterpret_cast<const u32x2*>(b1);
          ue = u32x4{lo.x, lo.y, hi.x, hi.y};
        } else if constexpr (CLS == 2) {               // (g,th-1),(g,th) e=1 pairs
          const int r0 = rowb(2 * G, dl), r1 = rowb(2 * G + 1, dl);
          ue = u32x4{col[r0 + 2 * th - 1], col[r0 + 2 * th + 1],
                     col[r1 + 2 * th - 1], col[r1 + 2 * th + 1]};
        } else {                                       // g ascending, e=1, t=th
          #pragma unroll
          for (int d = 0; d < 4; ++d) {
            int gg = 4 * G + d; gg = (gg > 23) ? 23 : gg;  // k>=48 -> A==0, row dontcare
            ue[d] = col[rowb(gg, dl) + 2 * th + 1];
          }
        }
        acc[dl][blk] = __builtin_amdgcn_mfma_f32_16x16x32_bf16(af[s], __builtin_bit_cast(bf16x8, ue), acc[dl][blk], 0, 0, 0);
      }
    }
  }

  // D rows 0-7 = co (even ow), 8-15 = co (odd ow); row = q*4+j, col = c15.
  const int isO = (q >= 2);
  const int co0 = (q & 1) * 4;
  #pragma unroll
  for (int dl = 0; dl < 3; ++dl) {
    #pragma unroll
    for (int blk = 0; blk < 3; ++blk) {
      const int ow = blk * 32 + 2 * c15 + isO;
      if (ow < 95) {
        const long ob = (long)(f0 + dl) * OFS + (long)od * ODS + (long)oh * HO + ow;
        #pragma unroll
        for (int j = 0; j < 4; ++j)
          out[(long)(co0 + j) * OCS + ob] = acc[dl][blk][j];
      }
    }
  }
}

constexpr int NBLK = 2 * 24 * 24;                      // f-triple x od-pair x og = 1152

__global__ __launch_bounds__(512) void convt4d_kernel(
    const float* __restrict__ x, const unsigned short* __restrict__ A,
    float* __restrict__ out)
{
  __shared__ u32 lds[48 * NRSTR];                      // 46464 B

  constexpr int qq = NBLK / 8;                         // 144 (NBLK%8==0)
  const int bid = blockIdx.x;
  const int L = (bid & 7) * qq + (bid >> 3);           // bijective XCD swizzle
  const int og = L % 24;
  const int rest = L / 24;
  const int odp = rest % 24, fp = rest / 24;           // od pair {2odp,2odp+1}; f-triple
  const int f0 = 3 * fp;                               // f0 in {0,3}; frames f0..f0+4

  const int tid = threadIdx.x;
  const int ihb = og * 2;
  const int idp = odp + 1;                             // e=0 plane = p+1, e=1 plane = p

  // stage 240-row union PRE-PACKED + TRANSPOSED: lds[n*NRSTR + row] =
  //   bf(x[n]) | bf(x[n+1])<<16 ; row = (ci*5 + fi)*6 + t*2 + e, fi = frame - f0 (0..4)
  for (int c = tid; c < 240 * 12; c += 512) {
    const int row = c / 12, ch = c % 12;
    const int ggp = row / 6;
    const int rem = row % 6;
    const int t = rem >> 1, e = rem & 1;
    const int ci = ggp / 5, fi = ggp % 5;
    int plane = idp - e; if (plane > 23) plane = 23;   // odp=23,e=0: unused, clamp OOB
    int ih = ihb + t; if (ih > 47) ih = 47;            // og=23 t=2: unused, clamp
    const float* src = x + ci * XCS + (f0 + fi) * XFS + plane * XDS + ih * W_ + ch * 4;
    const f4a v = *reinterpret_cast<const f4a*>(src);
    const float v4 = (ch == 11) ? 0.f : src[4];        // x[48] slot must be 0 (n=47 pair)
    const u32 b0 = __float_as_uint(v.x), b1 = __float_as_uint(v.y);
    const u32 b2 = __float_as_uint(v.z), b3 = __float_as_uint(v.w);
    const u32 b4 = __float_as_uint(v4);
    u32* dst = lds + (4 * ch) * NRSTR + row;
    dst[0 * NRSTR] = __builtin_amdgcn_perm(b1, b0, 0x07060302u);
    dst[1 * NRSTR] = __builtin_amdgcn_perm(b2, b1, 0x07060302u);
    dst[2 * NRSTR] = __builtin_amdgcn_perm(b3, b2, 0x07060302u);
    dst[3 * NRSTR] = __builtin_amdgcn_perm(b4, b3, 0x07060302u);
  }
  __syncthreads();

  const int w = tid >> 6, lane = tid & 63;
  const int half = w >> 2;                             // 0: od=2p (pd0), 1: od=2p+1 (pd1)
  const int od = 2 * odp + half;
  if (od > 46) return;                                 // odp=23 pd1 half: no od=47
  int oh = og * 4 + (w & 3);
  if (oh > 94) oh = 93;                                // og=23,w&3=3: dup of w&3=1 (benign)
  if (half) {
    if (oh & 1) wave_body<1, 1>(lds, A, out, f0, od, oh, ihb, lane);
    else        wave_body<1, 0>(lds, A, out, f0, od, oh, ihb, lane);
  } else {
    if (oh & 1) wave_body<0, 1>(lds, A, out, f0, od, oh, ihb, lane);
    else        wave_body<0, 0>(lds, A, out, f0, od, oh, ihb, lane);
  }
}
}  // namespace

extern "C" void kernel_launch(void* const* d_in, const int* in_sizes, int n_in,
                              void* d_out, int out_size, void* d_ws, size_t ws_size,
                              hipStream_t stream) {
  const float* x = (const float*)d_in[0];
  const float* w = (const float*)d_in[1];
  float* out = (float*)d_out;
  unsigned short* A = (unsigned short*)d_ws;           // 7168 shorts = 14 KB
  hipLaunchKernelGGL(pack_kernel, dim3(8), dim3(256), 0, stream, w, A);
  hipLaunchKernelGGL(convt4d_kernel, dim3(NBLK), dim3(512), 0, stream, x, A, out);
}